// Round 8
// baseline (809.841 us; speedup 1.0000x reference)
//
#include <hip/hip_runtime.h>
#include <hip/hip_cooperative_groups.h>

namespace cg = cooperative_groups;

#define NN 50000
#define NE 800000
#define NG 2048
#define F 64

constexpr int NB = (NN + 255) / 256;   // 196 scan chunks
constexpr int CG = 1024;               // csr_build blocks (co-resident: <=2048)
constexpr int CT = 256;

typedef float f4 __attribute__((ext_vector_type(4)));

// ================= cooperative CSR build + preprocessing =================
// Phases: A zero(deg,pooled) | B degree atomics | C dinv+scalex+chunk partials
//         | E scan partials (block 0) | F rowptr/cursor | G fill
__global__ void __launch_bounds__(CT, 8)
csr_build(const int* __restrict__ src, const int* __restrict__ dst,
          const float4* __restrict__ x4,
          int* __restrict__ deg, float* __restrict__ dinv, float4* __restrict__ xd4,
          int* __restrict__ rowptr, int* __restrict__ cursor, int* __restrict__ col,
          int* __restrict__ partial, float* __restrict__ pooled_counts) {
    cg::grid_group grid = cg::this_grid();
    __shared__ int s[CT];
    const int t = threadIdx.x, b = blockIdx.x;
    const int gtid = b * CT + t, gsz = CG * CT;

    // A: zero deg + pooled/counts
    for (int i = gtid; i < NN; i += gsz) deg[i] = 0;
    for (int i = gtid; i < NG * F + NG; i += gsz) pooled_counts[i] = 0.f;
    grid.sync();

    // B: in-degree atomics
    for (int e = gtid; e < NE; e += gsz) atomicAdd(&deg[dst[e]], 1);
    grid.sync();

    // C: dinv, xd = dinv*x, per-chunk partial sums of deg
    for (int i = gtid; i < NN; i += gsz) dinv[i] = rsqrtf((float)(deg[i] + 1));
    for (int i = gtid; i < NN * 8; i += gsz) {
        int v = i >> 3;
        float d = rsqrtf((float)(deg[v] + 1));
        float4 a = x4[i];
        a.x *= d; a.y *= d; a.z *= d; a.w *= d;
        xd4[i] = a;
    }
    for (int c = b; c < NB; c += CG) {
        int i = c * 256 + t;
        s[t] = (i < NN) ? deg[i] : 0;
        __syncthreads();
        for (int off = 128; off > 0; off >>= 1) {
            if (t < off) s[t] += s[t + off];
            __syncthreads();
        }
        if (t == 0) partial[c] = s[0];
        __syncthreads();
    }
    grid.sync();

    // E: exclusive scan of partial[NB] (block 0 only; NB<=256)
    if (b == 0) {
        int v = (t < NB) ? partial[t] : 0;
        s[t] = v;
        __syncthreads();
        for (int off = 1; off < 256; off <<= 1) {
            int x = (t >= off) ? s[t - off] : 0;
            __syncthreads();
            s[t] += x;
            __syncthreads();
        }
        if (t < NB) partial[t] = s[t] - v;
        if (t == 0) rowptr[NN] = NE;
    }
    grid.sync();

    // F: rowptr + cursor via per-chunk scan + chunk offset
    for (int c = b; c < NB; c += CG) {
        int i = c * 256 + t;
        int v = (i < NN) ? deg[i] : 0;
        s[t] = v;
        __syncthreads();
        for (int off = 1; off < 256; off <<= 1) {
            int x = (t >= off) ? s[t - off] : 0;
            __syncthreads();
            s[t] += x;
            __syncthreads();
        }
        if (i < NN) {
            int rp = partial[c] + s[t] - v;
            rowptr[i] = rp;
            cursor[i] = rp;
        }
        __syncthreads();
    }
    grid.sync();

    // G: scatter edges into CSR slots
    for (int e = gtid; e < NE; e += gsz) {
        int sv = src[e];
        int slot = atomicAdd(&cursor[dst[e]], 1);
        col[slot] = sv;
    }
}

// ---------------- layer-1 aggregation over raw xd (32 feats = 8 f4) ------------
// s[v] = dinv[v] * (sum_{u->v} xd[u] + xd[v]);  8 slots x 8 f4-lanes.
__global__ void agg32_kernel(const f4* __restrict__ g4, const int* __restrict__ rowptr,
                             const int* __restrict__ col, const float* __restrict__ dinv,
                             float* __restrict__ out) {
    int lane = threadIdx.x & 63;
    int v = blockIdx.x * 4 + (threadIdx.x >> 6);
    int slot = lane >> 3, fq = lane & 7;
    int beg = rowptr[v], end = rowptr[v + 1];
    f4 acc = {0.f, 0.f, 0.f, 0.f};
    for (int base = beg; base < end; base += 32) {
        f4 a[4];
        float w[4];
#pragma unroll
        for (int j = 0; j < 4; ++j) {
            int e = base + slot + j * 8;
            int ce = (e < end) ? e : (end - 1);
            w[j] = (e < end) ? 1.f : 0.f;
            int u = col[ce];
            a[j] = g4[(long)u * 8 + fq];
        }
#pragma unroll
        for (int j = 0; j < 4; ++j) acc += w[j] * a[j];
    }
#pragma unroll
    for (int m = 8; m < 64; m <<= 1) {
        acc.x += __shfl_xor(acc.x, m);
        acc.y += __shfl_xor(acc.y, m);
        acc.z += __shfl_xor(acc.z, m);
        acc.w += __shfl_xor(acc.w, m);
    }
    f4 self = g4[(long)v * 8 + fq];
    float d = dinv[v];
    acc = d * (acc + self);
    if (slot < 4) {   // 32 distinct scalars = one 128B line
        float comp = (slot == 0) ? acc.x : (slot == 1) ? acc.y : (slot == 2) ? acc.z : acc.w;
        out[(long)v * 32 + 4 * fq + slot] = comp;
    }
}

// ---------------- aggregation (64 feats = 16 f4), optional pool fuse ----------
// h[v] = relu(dinv[v]*(sum g[u] + g[v]) + b);  4 slots x 16 f4-lanes; no write amp.
template <bool POOL>
__global__ void agg4_kernel(const f4* __restrict__ g4, const int* __restrict__ rowptr,
                            const int* __restrict__ col, const float* __restrict__ dinv,
                            const f4* __restrict__ bias4, float* __restrict__ out,
                            const int* __restrict__ batch, float* __restrict__ pooled,
                            float* __restrict__ counts) {
    int lane = threadIdx.x & 63;
    int v = blockIdx.x * 4 + (threadIdx.x >> 6);
    int slot = lane >> 4, fq = lane & 15;
    int beg = rowptr[v], end = rowptr[v + 1];
    f4 acc = {0.f, 0.f, 0.f, 0.f};
    for (int base = beg; base < end; base += 32) {
        f4 a[8];
        float w[8];
#pragma unroll
        for (int j = 0; j < 8; ++j) {
            int e = base + slot + j * 4;
            int ce = (e < end) ? e : (end - 1);
            w[j] = (e < end) ? 1.f : 0.f;
            int u = col[ce];
            a[j] = g4[(long)u * 16 + fq];
        }
#pragma unroll
        for (int j = 0; j < 8; ++j) acc += w[j] * a[j];
    }
#pragma unroll
    for (int m = 16; m < 64; m <<= 1) {
        acc.x += __shfl_xor(acc.x, m);
        acc.y += __shfl_xor(acc.y, m);
        acc.z += __shfl_xor(acc.z, m);
        acc.w += __shfl_xor(acc.w, m);
    }
    f4 self = g4[(long)v * 16 + fq];
    float d = dinv[v];
    f4 bb = bias4[fq];
    f4 hv;
    hv.x = fmaxf(fmaf(d, acc.x + self.x, bb.x), 0.f);
    hv.y = fmaxf(fmaf(d, acc.y + self.y, bb.y), 0.f);
    hv.z = fmaxf(fmaf(d, acc.z + self.z, bb.z), 0.f);
    hv.w = fmaxf(fmaf(d, acc.w + self.w, bb.w), 0.f);
    float comp = (slot == 0) ? hv.x : (slot == 1) ? hv.y : (slot == 2) ? hv.z : hv.w;
    if (POOL) {
        int b = batch[v];
        atomicAdd(&pooled[(long)b * F + 4 * fq + slot], comp);
        if (lane == 0) atomicAdd(&counts[b], 1.0f);
    } else {
        out[(long)v * F + 4 * fq + slot] = comp;   // 64 lanes, 64 scalars, 256B region
    }
}

// ---------------- GEMM: 16 nodes/block, 256 threads -------------------------------
template <int K, bool RELU_BIAS>
__global__ void gemm_kernel(const float* __restrict__ in, const float* __restrict__ W,
                            const float* __restrict__ bias, const float* __restrict__ dinv,
                            float* __restrict__ out) {
    __shared__ float Ws[K * F];
    int t = threadIdx.x;
#pragma unroll
    for (int i = 0; i < K * F / 256; ++i) Ws[i * 256 + t] = W[i * 256 + t];
    __syncthreads();
    int f = t & 63;
    int slot = __builtin_amdgcn_readfirstlane(t >> 6);  // wave-uniform
    int n0 = blockIdx.x * 16 + slot;
    float acc0 = 0.f, acc1 = 0.f, acc2 = 0.f, acc3 = 0.f;
    const float* r0 = in + (long)n0 * K;
    const float* r1 = r0 + 4 * K;
    const float* r2 = r0 + 8 * K;
    const float* r3 = r0 + 12 * K;
#pragma unroll
    for (int k = 0; k < K; ++k) {
        float w = Ws[k * F + f];
        acc0 = fmaf(r0[k], w, acc0);
        acc1 = fmaf(r1[k], w, acc1);
        acc2 = fmaf(r2[k], w, acc2);
        acc3 = fmaf(r3[k], w, acc3);
    }
    if (RELU_BIAS) {
        float b = bias[f];
        out[(long)n0 * F + f]        = fmaxf(acc0 + b, 0.f);
        out[(long)(n0 + 4) * F + f]  = fmaxf(acc1 + b, 0.f);
        out[(long)(n0 + 8) * F + f]  = fmaxf(acc2 + b, 0.f);
        out[(long)(n0 + 12) * F + f] = fmaxf(acc3 + b, 0.f);
    } else {
        out[(long)n0 * F + f]        = dinv[n0] * acc0;
        out[(long)(n0 + 4) * F + f]  = dinv[n0 + 4] * acc1;
        out[(long)(n0 + 8) * F + f]  = dinv[n0 + 8] * acc2;
        out[(long)(n0 + 12) * F + f] = dinv[n0 + 12] * acc3;
    }
}

// ---------------- head: out = relu(pooled/cnt @ lw1 + lb1) @ lw2 + lb2 ------------
__global__ void head_kernel(const float* __restrict__ pooled, const float* __restrict__ counts,
                            const float* __restrict__ lw1, const float* __restrict__ lb1,
                            const float* __restrict__ lw2, const float* __restrict__ lb2,
                            float* __restrict__ out) {
    __shared__ float p[F];
    __shared__ float hid[F];
    int gid = blockIdx.x, t = threadIdx.x;
    float cnt = fmaxf(counts[gid], 1.0f);
    p[t] = pooled[(long)gid * F + t] / cnt;
    __syncthreads();
    float acc = lb1[t];
#pragma unroll 8
    for (int k = 0; k < F; ++k) acc = fmaf(p[k], lw1[k * F + t], acc);
    hid[t] = fmaxf(acc, 0.f);
    __syncthreads();
    if (t < 2) {
        float a = lb2[t];
#pragma unroll 8
        for (int k = 0; k < F; ++k) a = fmaf(hid[k], lw2[k * 2 + t], a);
        out[(long)gid * 2 + t] = a;
    }
}

extern "C" void kernel_launch(void* const* d_in, const int* in_sizes, int n_in,
                              void* d_out, int out_size, void* d_ws, size_t ws_size,
                              hipStream_t stream) {
    const float* x    = (const float*)d_in[0];
    const int*   ei   = (const int*)d_in[1];   // [2, NE]: src then dst
    const int*   bat  = (const int*)d_in[2];
    const float* W1   = (const float*)d_in[3];
    const float* b1   = (const float*)d_in[4];
    const float* W2   = (const float*)d_in[5];
    const float* b2   = (const float*)d_in[6];
    const float* W3   = (const float*)d_in[7];
    const float* b3   = (const float*)d_in[8];
    const float* lw1  = (const float*)d_in[9];
    const float* lb1  = (const float*)d_in[10];
    const float* lw2  = (const float*)d_in[11];
    const float* lb2  = (const float*)d_in[12];
    float* out = (float*)d_out;

    // workspace carve-up (256B aligned)
    char* ws = (char*)d_ws;
    size_t off = 0;
    auto carve = [&](size_t bytes) {
        void* p = ws + off;
        off += (bytes + 255) & ~(size_t)255;
        return p;
    };
    int*   deg     = (int*)carve(NN * 4);
    float* dinv    = (float*)carve(NN * 4);
    int*   rowptr  = (int*)carve((NN + 1) * 4);
    int*   cursor  = (int*)carve(NN * 4);
    int*   partial = (int*)carve(256 * 4);
    int*   col     = (int*)carve((size_t)NE * 4);
    float* xd      = (float*)carve((size_t)NN * 32 * 4);
    float* sbuf    = (float*)carve((size_t)NN * 32 * 4);
    float* bufA    = (float*)carve((size_t)NN * F * 4);
    float* bufB    = (float*)carve((size_t)NN * F * 4);
    float* pooled  = (float*)carve((size_t)NG * F * 4 + NG * 4);
    float* counts  = pooled + (size_t)NG * F;

    // ---- single cooperative kernel: zero + degree + dinv + scalex + scan + fill ----
    {
        const int* srcp = ei;
        const int* dstp = ei + NE;
        const float4* x4p = (const float4*)x;
        float4* xd4p = (float4*)xd;
        void* args[] = {(void*)&srcp, (void*)&dstp, (void*)&x4p,
                        (void*)&deg, (void*)&dinv, (void*)&xd4p,
                        (void*)&rowptr, (void*)&cursor, (void*)&col,
                        (void*)&partial, (void*)&pooled};
        hipLaunchCooperativeKernel((void*)csr_build, dim3(CG), dim3(CT), args, 0, stream);
    }

    const int gridN = NN / 4;     // 12500 blocks, 4 nodes (waves) each
    const int gridG = NN / 16;    // 3125 blocks for gemm

    // layer 1: aggregate raw 32-feat xd, then GEMM with fused bias+relu
    agg32_kernel<<<gridN, 256, 0, stream>>>((const f4*)xd, rowptr, col, dinv, sbuf);
    gemm_kernel<32, true><<<gridG, 256, 0, stream>>>(sbuf, W1, b1, dinv, bufA);

    // layer 2: g = dinv*(h1@W2), aggregate with bias+relu
    gemm_kernel<64, false><<<gridG, 256, 0, stream>>>(bufA, W2, nullptr, dinv, bufB);
    agg4_kernel<false><<<gridN, 256, 0, stream>>>((const f4*)bufB, rowptr, col, dinv,
                                                  (const f4*)b2, bufA,
                                                  nullptr, nullptr, nullptr);
    // layer 3: fused mean-pool accumulation
    gemm_kernel<64, false><<<gridG, 256, 0, stream>>>(bufA, W3, nullptr, dinv, bufB);
    agg4_kernel<true><<<gridN, 256, 0, stream>>>((const f4*)bufB, rowptr, col, dinv,
                                                 (const f4*)b3, nullptr,
                                                 bat, pooled, counts);
    // head MLP
    head_kernel<<<NG, 64, 0, stream>>>(pooled, counts, lw1, lb1, lw2, lb2, out);
}

// Round 9
// 443.933 us; speedup vs baseline: 1.8242x; 1.8242x over previous
//
#include <hip/hip_runtime.h>

#define NN 50000
#define NE 800000
#define NG 2048
#define F 64

constexpr int NB = (NN + 255) / 256;  // 196 scan blocks

typedef float f4 __attribute__((ext_vector_type(4)));

// ---------------- degree (edge-only in-degree) ----------------
__global__ void deg_kernel(const int* __restrict__ dst, int* __restrict__ deg) {
    int e = blockIdx.x * 256 + threadIdx.x;
    if (e < NE) atomicAdd(&deg[dst[e]], 1);
}

// dinv[v] = rsqrt(deg+1); xd half-major [2][NN][16]: xd[((h*NN)+v)*16 + fl]
__global__ void scalex_kernel(const int* __restrict__ deg, const float4* __restrict__ x4,
                              float* __restrict__ dinv, f4* __restrict__ xdh) {
    int i = blockIdx.x * 256 + threadIdx.x;   // f4 index over NN*8
    if (i < NN * 8) {
        int v = i >> 3, ff = i & 7;
        float d = rsqrtf((float)(deg[v] + 1));
        if (ff == 0) dinv[v] = d;
        float4 a = x4[i];
        f4 b = {a.x * d, a.y * d, a.z * d, a.w * d};
        int h = ff >> 2, fj = ff & 3;
        xdh[((long)h * NN + v) * 4 + fj] = b;
    }
}

// ---------------- 3-kernel exclusive scan of deg -> rowptr ----------------
__global__ void scan1_kernel(const int* __restrict__ deg, int* __restrict__ bsums) {
    __shared__ int s[256];
    int t = threadIdx.x, i = blockIdx.x * 256 + t;
    s[t] = (i < NN) ? deg[i] : 0;
    __syncthreads();
    for (int off = 128; off > 0; off >>= 1) {
        if (t < off) s[t] += s[t + off];
        __syncthreads();
    }
    if (t == 0) bsums[blockIdx.x] = s[0];
}

__global__ void scan2_kernel(int* __restrict__ bsums, int* __restrict__ rowptr) {
    __shared__ int s[256];
    int t = threadIdx.x;
    int v = (t < NB) ? bsums[t] : 0;
    s[t] = v;
    __syncthreads();
    for (int off = 1; off < 256; off <<= 1) {
        int x = (t >= off) ? s[t - off] : 0;
        __syncthreads();
        s[t] += x;
        __syncthreads();
    }
    if (t < NB) bsums[t] = s[t] - v;
    if (t == 0) rowptr[NN] = NE;
}

__global__ void scan3_kernel(const int* __restrict__ deg, const int* __restrict__ bsums,
                             int* __restrict__ rowptr, int* __restrict__ cursor) {
    __shared__ int s[256];
    int t = threadIdx.x, i = blockIdx.x * 256 + t;
    int v = (i < NN) ? deg[i] : 0;
    s[t] = v;
    __syncthreads();
    for (int off = 1; off < 256; off <<= 1) {
        int x = (t >= off) ? s[t - off] : 0;
        __syncthreads();
        s[t] += x;
        __syncthreads();
    }
    if (i < NN) {
        int rp = bsums[blockIdx.x] + s[t] - v;
        rowptr[i] = rp;
        cursor[i] = rp;
    }
}

__global__ void fill_kernel(const int* __restrict__ src, const int* __restrict__ dst,
                            int* __restrict__ cursor, int* __restrict__ col) {
    int e = blockIdx.x * 256 + threadIdx.x;
    if (e < NE) {
        int slot = atomicAdd(&cursor[dst[e]], 1);
        col[slot] = src[e];
    }
}

// ---------------- layer-1 aggregation, half-split, half-major xd ----------------
// s[v] = dinv[v]*(sum xd[u] + xd[v]); each block: 16 of 32 feats (contiguous 3.2MB half).
// grid 25000: bi&7 -> XCD; half = (bi&7)>>2; 16 edge slots x 4 f4-lanes.
__global__ void agg32_kernel(const f4* __restrict__ xdh, const int* __restrict__ rowptr,
                             const int* __restrict__ col, const float* __restrict__ dinv,
                             float* __restrict__ out) {
    int tid = threadIdx.x, lane = tid & 63;
    int bi = blockIdx.x;
    int h = (bi & 7) >> 2;
    int vg = ((bi >> 3) << 2) | (bi & 3);   // 0..12499
    int v = vg * 4 + (tid >> 6);
    int slot = lane >> 2, fj = lane & 3;
    const f4* gbase = xdh + (long)h * NN * 4;
    int beg = rowptr[v], end = rowptr[v + 1];
    f4 acc = {0.f, 0.f, 0.f, 0.f};
    for (int base = beg; base < end; base += 32) {
        f4 a[2];
        float w[2];
#pragma unroll
        for (int j = 0; j < 2; ++j) {
            int e = base + slot + j * 16;
            int ce = (e < end) ? e : (end - 1);
            w[j] = (e < end) ? 1.f : 0.f;
            int u = col[ce];
            a[j] = gbase[(long)u * 4 + fj];   // 64B from contiguous L2-resident half
        }
        acc += w[0] * a[0] + w[1] * a[1];
    }
#pragma unroll
    for (int m = 4; m < 64; m <<= 1) {
        acc.x += __shfl_xor(acc.x, m);
        acc.y += __shfl_xor(acc.y, m);
        acc.z += __shfl_xor(acc.z, m);
        acc.w += __shfl_xor(acc.w, m);
    }
    f4 self = gbase[(long)v * 4 + fj];
    float d = dinv[v];
    acc = d * (acc + self);
    if (slot < 4) {   // 16 scalars = one 64B line (row-major sbuf for gemm1)
        float comp = (slot == 0) ? acc.x : (slot == 1) ? acc.y : (slot == 2) ? acc.z : acc.w;
        out[(long)v * 32 + h * 16 + fj * 4 + slot] = comp;
    }
}

// ---------------- aggregation, quarter-split, quarter-major g -------------------
// h[v] = relu(dinv[v]*(sum g[u]+g[v])+b); block handles 16 of 64 feats.
// g layout [4][NN][16]; quarter = contiguous 3.2MB -> one XCD L2.
// grid 50000: q=(bi&7)>>1 pinned to XCD pair; 16 edge slots x 4 f4-lanes.
template <bool POOL>
__global__ void agg4_kernel(const f4* __restrict__ gq, const int* __restrict__ rowptr,
                            const int* __restrict__ col, const float* __restrict__ dinv,
                            const f4* __restrict__ bias4, float* __restrict__ out,
                            const int* __restrict__ batch, float* __restrict__ pooled,
                            float* __restrict__ counts) {
    int tid = threadIdx.x, lane = tid & 63;
    int bi = blockIdx.x;
    int q = (bi & 7) >> 1;
    int vg = ((bi >> 3) << 1) | (bi & 1);   // 0..12499
    int v = vg * 4 + (tid >> 6);
    int slot = lane >> 2, fj = lane & 3;
    const f4* gbase = gq + (long)q * NN * 4;
    int beg = rowptr[v], end = rowptr[v + 1];
    f4 acc = {0.f, 0.f, 0.f, 0.f};
    for (int base = beg; base < end; base += 32) {
        f4 a[2];
        float w[2];
#pragma unroll
        for (int j = 0; j < 2; ++j) {
            int e = base + slot + j * 16;
            int ce = (e < end) ? e : (end - 1);
            w[j] = (e < end) ? 1.f : 0.f;
            int u = col[ce];
            a[j] = gbase[(long)u * 4 + fj];   // 64B from contiguous L2-resident quarter
        }
        acc += w[0] * a[0] + w[1] * a[1];
    }
#pragma unroll
    for (int m = 4; m < 64; m <<= 1) {
        acc.x += __shfl_xor(acc.x, m);
        acc.y += __shfl_xor(acc.y, m);
        acc.z += __shfl_xor(acc.z, m);
        acc.w += __shfl_xor(acc.w, m);
    }
    f4 self = gbase[(long)v * 4 + fj];
    float d = dinv[v];
    f4 bb = bias4[q * 4 + fj];
    f4 hv;
    hv.x = fmaxf(fmaf(d, acc.x + self.x, bb.x), 0.f);
    hv.y = fmaxf(fmaf(d, acc.y + self.y, bb.y), 0.f);
    hv.z = fmaxf(fmaf(d, acc.z + self.z, bb.z), 0.f);
    hv.w = fmaxf(fmaf(d, acc.w + self.w, bb.w), 0.f);
    if (slot < 4) {   // 16 scalars = one 64B line
        float comp = (slot == 0) ? hv.x : (slot == 1) ? hv.y : (slot == 2) ? hv.z : hv.w;
        int feat = q * 16 + fj * 4 + slot;
        if (POOL) {
            atomicAdd(&pooled[(long)batch[v] * F + feat], comp);
        } else {
            out[(long)v * F + feat] = comp;   // row-major h for next gemm
        }
    }
    if (POOL && q == 0 && lane == 0) atomicAdd(&counts[batch[v]], 1.0f);
}

// ---------------- GEMM: 16 nodes/block, 256 threads -------------------------------
// RELU_BIAS: out = relu(in@W + b), row-major out (layer-1)
// else:      out = dinv[n]*(in@W), QUARTER-MAJOR out [4][NN][16] for agg4
template <int K, bool RELU_BIAS>
__global__ void gemm_kernel(const float* __restrict__ in, const float* __restrict__ W,
                            const float* __restrict__ bias, const float* __restrict__ dinv,
                            float* __restrict__ out) {
    __shared__ float Ws[K * F];
    int t = threadIdx.x;
#pragma unroll
    for (int i = 0; i < K * F / 256; ++i) Ws[i * 256 + t] = W[i * 256 + t];
    __syncthreads();
    int f = t & 63;
    int slot = __builtin_amdgcn_readfirstlane(t >> 6);  // wave-uniform
    int n0 = blockIdx.x * 16 + slot;                    // nodes n0, n0+4, n0+8, n0+12
    float acc0 = 0.f, acc1 = 0.f, acc2 = 0.f, acc3 = 0.f;
    const float* r0 = in + (long)n0 * K;
    const float* r1 = r0 + 4 * K;
    const float* r2 = r0 + 8 * K;
    const float* r3 = r0 + 12 * K;
#pragma unroll
    for (int k = 0; k < K; ++k) {
        float w = Ws[k * F + f];
        acc0 = fmaf(r0[k], w, acc0);
        acc1 = fmaf(r1[k], w, acc1);
        acc2 = fmaf(r2[k], w, acc2);
        acc3 = fmaf(r3[k], w, acc3);
    }
    if (RELU_BIAS) {
        float b = bias[f];
        out[(long)n0 * F + f]        = fmaxf(acc0 + b, 0.f);
        out[(long)(n0 + 4) * F + f]  = fmaxf(acc1 + b, 0.f);
        out[(long)(n0 + 8) * F + f]  = fmaxf(acc2 + b, 0.f);
        out[(long)(n0 + 12) * F + f] = fmaxf(acc3 + b, 0.f);
    } else {
        int q = f >> 4, fl = f & 15;
        float* o = out + (long)q * NN * 16 + fl;
        o[(long)n0 * 16]        = dinv[n0] * acc0;
        o[(long)(n0 + 4) * 16]  = dinv[n0 + 4] * acc1;
        o[(long)(n0 + 8) * 16]  = dinv[n0 + 8] * acc2;
        o[(long)(n0 + 12) * 16] = dinv[n0 + 12] * acc3;
    }
}

// ---------------- head: out = relu(pooled/cnt @ lw1 + lb1) @ lw2 + lb2 ------------
__global__ void head_kernel(const float* __restrict__ pooled, const float* __restrict__ counts,
                            const float* __restrict__ lw1, const float* __restrict__ lb1,
                            const float* __restrict__ lw2, const float* __restrict__ lb2,
                            float* __restrict__ out) {
    __shared__ float p[F];
    __shared__ float hid[F];
    int gid = blockIdx.x, t = threadIdx.x;
    float cnt = fmaxf(counts[gid], 1.0f);
    p[t] = pooled[(long)gid * F + t] / cnt;
    __syncthreads();
    float acc = lb1[t];
#pragma unroll 8
    for (int k = 0; k < F; ++k) acc = fmaf(p[k], lw1[k * F + t], acc);
    hid[t] = fmaxf(acc, 0.f);
    __syncthreads();
    if (t < 2) {
        float a = lb2[t];
#pragma unroll 8
        for (int k = 0; k < F; ++k) a = fmaf(hid[k], lw2[k * 2 + t], a);
        out[(long)gid * 2 + t] = a;
    }
}

extern "C" void kernel_launch(void* const* d_in, const int* in_sizes, int n_in,
                              void* d_out, int out_size, void* d_ws, size_t ws_size,
                              hipStream_t stream) {
    const float* x    = (const float*)d_in[0];
    const int*   ei   = (const int*)d_in[1];   // [2, NE]: src then dst
    const int*   bat  = (const int*)d_in[2];
    const float* W1   = (const float*)d_in[3];
    const float* b1   = (const float*)d_in[4];
    const float* W2   = (const float*)d_in[5];
    const float* b2   = (const float*)d_in[6];
    const float* W3   = (const float*)d_in[7];
    const float* b3   = (const float*)d_in[8];
    const float* lw1  = (const float*)d_in[9];
    const float* lb1  = (const float*)d_in[10];
    const float* lw2  = (const float*)d_in[11];
    const float* lb2  = (const float*)d_in[12];
    float* out = (float*)d_out;

    const int* src = ei;
    const int* dst = ei + NE;

    // workspace carve-up (256B aligned)
    char* ws = (char*)d_ws;
    size_t off = 0;
    auto carve = [&](size_t bytes) {
        void* p = ws + off;
        off += (bytes + 255) & ~(size_t)255;
        return p;
    };
    int*   deg     = (int*)carve(NN * 4);
    float* dinv    = (float*)carve(NN * 4);
    int*   rowptr  = (int*)carve((NN + 1) * 4);
    int*   cursor  = (int*)carve(NN * 4);
    int*   bsums   = (int*)carve(256 * 4);
    int*   col     = (int*)carve((size_t)NE * 4);
    float* xd      = (float*)carve((size_t)NN * 32 * 4);   // half-major [2][NN][16]
    float* sbuf    = (float*)carve((size_t)NN * 32 * 4);   // row-major
    float* bufA    = (float*)carve((size_t)NN * F * 4);    // row-major h
    float* bufB    = (float*)carve((size_t)NN * F * 4);    // quarter-major g [4][NN][16]
    float* pooled  = (float*)carve((size_t)NG * F * 4 + NG * 4);
    float* counts  = pooled + (size_t)NG * F;

    hipMemsetAsync(deg, 0, NN * 4, stream);
    hipMemsetAsync(pooled, 0, ((size_t)NG * F + NG) * 4, stream);

    deg_kernel<<<(NE + 255) / 256, 256, 0, stream>>>(dst, deg);
    scalex_kernel<<<(NN * 8 + 255) / 256, 256, 0, stream>>>(deg, (const float4*)x, dinv, (f4*)xd);
    scan1_kernel<<<NB, 256, 0, stream>>>(deg, bsums);
    scan2_kernel<<<1, 256, 0, stream>>>(bsums, rowptr);
    scan3_kernel<<<NB, 256, 0, stream>>>(deg, bsums, rowptr, cursor);
    fill_kernel<<<(NE + 255) / 256, 256, 0, stream>>>(src, dst, cursor, col);

    const int gridH = 2 * (NN / 4);    // 25000 blocks (half x node-group)
    const int gridQ = 4 * (NN / 4);    // 50000 blocks (quarter x node-group)
    const int gridG = NN / 16;         // 3125 blocks

    // layer 1: half-split aggregation of xd, then GEMM with fused bias+relu
    agg32_kernel<<<gridH, 256, 0, stream>>>((const f4*)xd, rowptr, col, dinv, sbuf);
    gemm_kernel<32, true><<<gridG, 256, 0, stream>>>(sbuf, W1, b1, dinv, bufA);

    // layer 2: g = dinv*(h1@W2) quarter-major; quarter-split agg -> h2 row-major
    gemm_kernel<64, false><<<gridG, 256, 0, stream>>>(bufA, W2, nullptr, dinv, bufB);
    agg4_kernel<false><<<gridQ, 256, 0, stream>>>((const f4*)bufB, rowptr, col, dinv,
                                                  (const f4*)b2, bufA,
                                                  nullptr, nullptr, nullptr);
    // layer 3: same, final pass fuses mean-pool atomics
    gemm_kernel<64, false><<<gridG, 256, 0, stream>>>(bufA, W3, nullptr, dinv, bufB);
    agg4_kernel<true><<<gridQ, 256, 0, stream>>>((const f4*)bufB, rowptr, col, dinv,
                                                 (const f4*)b3, nullptr,
                                                 bat, pooled, counts);
    // head MLP
    head_kernel<<<NG, 64, 0, stream>>>(pooled, counts, lw1, lb1, lw2, lb2, out);
}

// Round 10
// 309.582 us; speedup vs baseline: 2.6159x; 1.4340x over previous
//
#include <hip/hip_runtime.h>

#define NN 50000
#define NE 800000
#define NG 2048
#define F 64

constexpr int NB = (NN + 255) / 256;  // 196 scan chunks

typedef float f4 __attribute__((ext_vector_type(4)));

// ---------------- degree (edge-only in-degree) ----------------
__global__ void deg_kernel(const int* __restrict__ dst, int* __restrict__ deg) {
    int e = blockIdx.x * 256 + threadIdx.x;
    if (e < NE) atomicAdd(&deg[dst[e]], 1);
}

// dinv[v] = rsqrt(deg+1); xd row-major = dinv*x
__global__ void scalex_kernel(const int* __restrict__ deg, const float4* __restrict__ x4,
                              float* __restrict__ dinv, float4* __restrict__ xd4) {
    int i = blockIdx.x * 256 + threadIdx.x;   // float4 index over NN*8
    if (i < NN * 8) {
        int v = i >> 3;
        float d = rsqrtf((float)(deg[v] + 1));
        if ((i & 7) == 0) dinv[v] = d;
        float4 a = x4[i];
        a.x *= d; a.y *= d; a.z *= d; a.w *= d;
        xd4[i] = a;
    }
}

// ---------------- scan: chunk sums, then fused (scan-of-sums + chunk scan) --------
__global__ void scan1_kernel(const int* __restrict__ deg, int* __restrict__ bsums) {
    __shared__ int s[256];
    int t = threadIdx.x, i = blockIdx.x * 256 + t;
    s[t] = (i < NN) ? deg[i] : 0;
    __syncthreads();
    for (int off = 128; off > 0; off >>= 1) {
        if (t < off) s[t] += s[t + off];
        __syncthreads();
    }
    if (t == 0) bsums[blockIdx.x] = s[0];
}

// merged scan2+scan3: every block scans the 196 chunk sums locally, then its chunk
__global__ void scan23_kernel(const int* __restrict__ deg, const int* __restrict__ bsums,
                              int* __restrict__ rowptr, int* __restrict__ cursor) {
    __shared__ int offs[256];
    __shared__ int s[256];
    int t = threadIdx.x, blk = blockIdx.x;
    offs[t] = (t < NB) ? bsums[t] : 0;
    __syncthreads();
    for (int o = 1; o < 256; o <<= 1) {
        int x = (t >= o) ? offs[t - o] : 0;
        __syncthreads();
        offs[t] += x;
        __syncthreads();
    }
    int chunk_off = (blk > 0) ? offs[blk - 1] : 0;   // exclusive offset of this chunk
    int i = blk * 256 + t;
    int v = (i < NN) ? deg[i] : 0;
    s[t] = v;
    __syncthreads();
    for (int o = 1; o < 256; o <<= 1) {
        int x = (t >= o) ? s[t - o] : 0;
        __syncthreads();
        s[t] += x;
        __syncthreads();
    }
    if (i < NN) {
        int rp = chunk_off + s[t] - v;
        rowptr[i] = rp;
        cursor[i] = rp;
    }
    if (blk == 0 && t == 0) rowptr[NN] = NE;
}

__global__ void fill_kernel(const int* __restrict__ src, const int* __restrict__ dst,
                            int* __restrict__ cursor, int* __restrict__ col) {
    int e = blockIdx.x * 256 + threadIdx.x;
    if (e < NE) {
        int slot = atomicAdd(&cursor[dst[e]], 1);
        col[slot] = src[e];
    }
}

// ---------------- layer-1 aggregation over raw xd (32 feats = 8 f4), r6 form ------
__global__ void agg32_kernel(const f4* __restrict__ g4, const int* __restrict__ rowptr,
                             const int* __restrict__ col, const float* __restrict__ dinv,
                             float* __restrict__ out) {
    int lane = threadIdx.x & 63;
    int v = blockIdx.x * 4 + (threadIdx.x >> 6);
    int slot = lane >> 3, fq = lane & 7;
    int beg = rowptr[v], end = rowptr[v + 1];
    f4 acc = {0.f, 0.f, 0.f, 0.f};
    for (int base = beg; base < end; base += 32) {
        f4 a[4];
        float w[4];
#pragma unroll
        for (int j = 0; j < 4; ++j) {
            int e = base + slot + j * 8;
            int ce = (e < end) ? e : (end - 1);
            w[j] = (e < end) ? 1.f : 0.f;
            int u = col[ce];
            a[j] = g4[(long)u * 8 + fq];
        }
#pragma unroll
        for (int j = 0; j < 4; ++j) acc += w[j] * a[j];
    }
#pragma unroll
    for (int m = 8; m < 64; m <<= 1) {
        acc.x += __shfl_xor(acc.x, m);
        acc.y += __shfl_xor(acc.y, m);
        acc.z += __shfl_xor(acc.z, m);
        acc.w += __shfl_xor(acc.w, m);
    }
    f4 self = g4[(long)v * 8 + fq];
    float d = dinv[v];
    acc = d * (acc + self);
    if (slot < 4) {
        float comp = (slot == 0) ? acc.x : (slot == 1) ? acc.y : (slot == 2) ? acc.z : acc.w;
        out[(long)v * 32 + 4 * fq + slot] = comp;
    }
}

// ---------------- agg4h: half-split (32 feats = 8 f4), 16 nodes per wave ----------
// g layout half-major [2][NN][32]; half h pinned to XCDs {4h..4h+3} via bi&7.
// grid 1568 blocks (196*8): h=(bi&7)>>2, idx=((bi>>3)<<2)|(bi&3) in [0,784).
// Each wave: nodes base..base+15; rowptr slice preloaded lane-parallel.
template <bool POOL>
__global__ void agg4h_kernel(const f4* __restrict__ g, const int* __restrict__ rowptr,
                             const int* __restrict__ col, const float* __restrict__ dinv,
                             const f4* __restrict__ bias4, float* __restrict__ out,
                             const int* __restrict__ batch, float* __restrict__ pooled,
                             float* __restrict__ counts) {
    int tid = threadIdx.x, lane = tid & 63, w = tid >> 6;
    int bi = blockIdx.x;
    int h = (bi & 7) >> 2;
    int idx = ((bi >> 3) << 2) | (bi & 3);
    int base = idx * 64 + w * 16;
    if (base >= NN) return;
    int slot = lane >> 3, fq = lane & 7;
    const f4* gb = g + (long)h * NN * 8;
    // lane-parallel rowptr preload: lane i<17 holds rowptr[base+i]
    int li = base + ((lane < 17) ? lane : 16);
    if (li > NN) li = NN;
    int rpv = rowptr[li];
#pragma unroll 1
    for (int i = 0; i < 16; ++i) {
        int v = base + i;
        if (v >= NN) break;
        int beg = __shfl(rpv, i), end = __shfl(rpv, i + 1);
        f4 acc = {0.f, 0.f, 0.f, 0.f};
        for (int b0 = beg; b0 < end; b0 += 32) {
            f4 a[4];
            float wt[4];
#pragma unroll
            for (int j = 0; j < 4; ++j) {
                int e = b0 + slot + j * 8;
                int ce = (e < end) ? e : (end - 1);
                wt[j] = (e < end) ? 1.f : 0.f;
                int u = col[ce];
                a[j] = gb[(long)u * 8 + fq];   // 128B row from pinned half-plane
            }
#pragma unroll
            for (int j = 0; j < 4; ++j) acc += wt[j] * a[j];
        }
#pragma unroll
        for (int m = 8; m < 64; m <<= 1) {
            acc.x += __shfl_xor(acc.x, m);
            acc.y += __shfl_xor(acc.y, m);
            acc.z += __shfl_xor(acc.z, m);
            acc.w += __shfl_xor(acc.w, m);
        }
        f4 self = gb[(long)v * 8 + fq];
        float d = dinv[v];
        f4 bb = bias4[h * 8 + fq];
        f4 hv;
        hv.x = fmaxf(fmaf(d, acc.x + self.x, bb.x), 0.f);
        hv.y = fmaxf(fmaf(d, acc.y + self.y, bb.y), 0.f);
        hv.z = fmaxf(fmaf(d, acc.z + self.z, bb.z), 0.f);
        hv.w = fmaxf(fmaf(d, acc.w + self.w, bb.w), 0.f);
        if (slot < 4) {   // 32 lanes, 32 distinct scalars = 128B line
            float comp = (slot == 0) ? hv.x : (slot == 1) ? hv.y : (slot == 2) ? hv.z : hv.w;
            int feat = h * 32 + fq * 4 + slot;
            if (POOL) {
                atomicAdd(&pooled[(long)batch[v] * F + feat], comp);
            } else {
                out[(long)v * F + feat] = comp;
            }
        }
        if (POOL && h == 0 && lane == 0) atomicAdd(&counts[batch[v]], 1.0f);
    }
}

// ---------------- GEMM: 16 nodes/block, 256 threads -------------------------------
// RELU_BIAS: out = relu(in@W + b), row-major (layer-1)
// else:      out = dinv[n]*(in@W), HALF-MAJOR [2][NN][32] for agg4h
template <int K, bool RELU_BIAS>
__global__ void gemm_kernel(const float* __restrict__ in, const float* __restrict__ W,
                            const float* __restrict__ bias, const float* __restrict__ dinv,
                            float* __restrict__ out) {
    __shared__ float Ws[K * F];
    int t = threadIdx.x;
#pragma unroll
    for (int i = 0; i < K * F / 256; ++i) Ws[i * 256 + t] = W[i * 256 + t];
    __syncthreads();
    int f = t & 63;
    int slot = __builtin_amdgcn_readfirstlane(t >> 6);  // wave-uniform
    int n0 = blockIdx.x * 16 + slot;                    // nodes n0, n0+4, n0+8, n0+12
    float acc0 = 0.f, acc1 = 0.f, acc2 = 0.f, acc3 = 0.f;
    const float* r0 = in + (long)n0 * K;
    const float* r1 = r0 + 4 * K;
    const float* r2 = r0 + 8 * K;
    const float* r3 = r0 + 12 * K;
#pragma unroll
    for (int k = 0; k < K; ++k) {
        float w = Ws[k * F + f];
        acc0 = fmaf(r0[k], w, acc0);
        acc1 = fmaf(r1[k], w, acc1);
        acc2 = fmaf(r2[k], w, acc2);
        acc3 = fmaf(r3[k], w, acc3);
    }
    if (RELU_BIAS) {
        float b = bias[f];
        out[(long)n0 * F + f]        = fmaxf(acc0 + b, 0.f);
        out[(long)(n0 + 4) * F + f]  = fmaxf(acc1 + b, 0.f);
        out[(long)(n0 + 8) * F + f]  = fmaxf(acc2 + b, 0.f);
        out[(long)(n0 + 12) * F + f] = fmaxf(acc3 + b, 0.f);
    } else {
        int hh = f >> 5, fl = f & 31;
        float* o = out + (long)hh * NN * 32 + fl;
        o[(long)n0 * 32]        = dinv[n0] * acc0;
        o[(long)(n0 + 4) * 32]  = dinv[n0 + 4] * acc1;
        o[(long)(n0 + 8) * 32]  = dinv[n0 + 8] * acc2;
        o[(long)(n0 + 12) * 32] = dinv[n0 + 12] * acc3;
    }
}

// ---------------- head: out = relu(pooled/cnt @ lw1 + lb1) @ lw2 + lb2 ------------
__global__ void head_kernel(const float* __restrict__ pooled, const float* __restrict__ counts,
                            const float* __restrict__ lw1, const float* __restrict__ lb1,
                            const float* __restrict__ lw2, const float* __restrict__ lb2,
                            float* __restrict__ out) {
    __shared__ float p[F];
    __shared__ float hid[F];
    int gid = blockIdx.x, t = threadIdx.x;
    float cnt = fmaxf(counts[gid], 1.0f);
    p[t] = pooled[(long)gid * F + t] / cnt;
    __syncthreads();
    float acc = lb1[t];
#pragma unroll 8
    for (int k = 0; k < F; ++k) acc = fmaf(p[k], lw1[k * F + t], acc);
    hid[t] = fmaxf(acc, 0.f);
    __syncthreads();
    if (t < 2) {
        float a = lb2[t];
#pragma unroll 8
        for (int k = 0; k < F; ++k) a = fmaf(hid[k], lw2[k * 2 + t], a);
        out[(long)gid * 2 + t] = a;
    }
}

extern "C" void kernel_launch(void* const* d_in, const int* in_sizes, int n_in,
                              void* d_out, int out_size, void* d_ws, size_t ws_size,
                              hipStream_t stream) {
    const float* x    = (const float*)d_in[0];
    const int*   ei   = (const int*)d_in[1];   // [2, NE]: src then dst
    const int*   bat  = (const int*)d_in[2];
    const float* W1   = (const float*)d_in[3];
    const float* b1   = (const float*)d_in[4];
    const float* W2   = (const float*)d_in[5];
    const float* b2   = (const float*)d_in[6];
    const float* W3   = (const float*)d_in[7];
    const float* b3   = (const float*)d_in[8];
    const float* lw1  = (const float*)d_in[9];
    const float* lb1  = (const float*)d_in[10];
    const float* lw2  = (const float*)d_in[11];
    const float* lb2  = (const float*)d_in[12];
    float* out = (float*)d_out;

    const int* src = ei;
    const int* dst = ei + NE;

    // workspace carve-up (256B aligned)
    char* ws = (char*)d_ws;
    size_t off = 0;
    auto carve = [&](size_t bytes) {
        void* p = ws + off;
        off += (bytes + 255) & ~(size_t)255;
        return p;
    };
    int*   deg     = (int*)carve(NN * 4);
    float* dinv    = (float*)carve(NN * 4);
    int*   rowptr  = (int*)carve((NN + 1) * 4);
    int*   cursor  = (int*)carve(NN * 4);
    int*   bsums   = (int*)carve(256 * 4);
    int*   col     = (int*)carve((size_t)NE * 4);
    float* xd      = (float*)carve((size_t)NN * 32 * 4);  // row-major
    float* sbuf    = (float*)carve((size_t)NN * 32 * 4);  // row-major
    float* bufA    = (float*)carve((size_t)NN * F * 4);   // row-major h
    float* bufB    = (float*)carve((size_t)NN * F * 4);   // half-major g [2][NN][32]
    float* pooled  = (float*)carve((size_t)NG * F * 4 + NG * 4);
    float* counts  = pooled + (size_t)NG * F;

    hipMemsetAsync(deg, 0, NN * 4, stream);
    hipMemsetAsync(pooled, 0, ((size_t)NG * F + NG) * 4, stream);

    deg_kernel<<<(NE + 255) / 256, 256, 0, stream>>>(dst, deg);
    scalex_kernel<<<(NN * 8 + 255) / 256, 256, 0, stream>>>(deg, (const float4*)x, dinv, (float4*)xd);
    scan1_kernel<<<NB, 256, 0, stream>>>(deg, bsums);
    scan23_kernel<<<NB, 256, 0, stream>>>(deg, bsums, rowptr, cursor);
    fill_kernel<<<(NE + 255) / 256, 256, 0, stream>>>(src, dst, cursor, col);

    const int gridN = NN / 4;      // 12500 blocks (agg32)
    const int gridH = 196 * 8;     // 1568 blocks (agg4h: 2 halves x 784 idx)
    const int gridG = NN / 16;     // 3125 blocks (gemm)

    // layer 1: aggregate raw 32-feat xd, then GEMM with fused bias+relu
    agg32_kernel<<<gridN, 256, 0, stream>>>((const f4*)xd, rowptr, col, dinv, sbuf);
    gemm_kernel<32, true><<<gridG, 256, 0, stream>>>(sbuf, W1, b1, dinv, bufA);

    // layer 2: g = dinv*(h1@W2) half-major; half-split 16-node agg with bias+relu
    gemm_kernel<64, false><<<gridG, 256, 0, stream>>>(bufA, W2, nullptr, dinv, bufB);
    agg4h_kernel<false><<<gridH, 256, 0, stream>>>((const f4*)bufB, rowptr, col, dinv,
                                                   (const f4*)b2, bufA,
                                                   nullptr, nullptr, nullptr);
    // layer 3: same, final fuses mean-pool atomics
    gemm_kernel<64, false><<<gridG, 256, 0, stream>>>(bufA, W3, nullptr, dinv, bufB);
    agg4h_kernel<true><<<gridH, 256, 0, stream>>>((const f4*)bufB, rowptr, col, dinv,
                                                  (const f4*)b3, nullptr,
                                                  bat, pooled, counts);
    // head MLP
    head_kernel<<<NG, 64, 0, stream>>>(pooled, counts, lw1, lb1, lw2, lb2, out);
}

// Round 11
// 304.288 us; speedup vs baseline: 2.6614x; 1.0174x over previous
//
#include <hip/hip_runtime.h>

#define NN 50000
#define NE 800000
#define NG 2048
#define F 64

constexpr int NB = (NN + 255) / 256;  // 196 scan chunks

typedef float f4 __attribute__((ext_vector_type(4)));

static __device__ __forceinline__ int ntload_i(const int* p) {
    return __builtin_nontemporal_load(p);
}

// ---------------- degree (edge-only in-degree) ----------------
__global__ void deg_kernel(const int* __restrict__ dst, int* __restrict__ deg) {
    int e = blockIdx.x * 256 + threadIdx.x;
    if (e < NE) atomicAdd(&deg[ntload_i(&dst[e])], 1);
}

// dinv[v] = rsqrt(deg+1); xd row-major = dinv*x
__global__ void scalex_kernel(const int* __restrict__ deg, const float4* __restrict__ x4,
                              float* __restrict__ dinv, float4* __restrict__ xd4) {
    int i = blockIdx.x * 256 + threadIdx.x;   // float4 index over NN*8
    if (i < NN * 8) {
        int v = i >> 3;
        float d = rsqrtf((float)(deg[v] + 1));
        if ((i & 7) == 0) dinv[v] = d;
        float4 a = x4[i];
        a.x *= d; a.y *= d; a.z *= d; a.w *= d;
        xd4[i] = a;
    }
}

// ---------------- scan: chunk sums, then fused (scan-of-sums + chunk scan) --------
__global__ void scan1_kernel(const int* __restrict__ deg, int* __restrict__ bsums) {
    __shared__ int s[256];
    int t = threadIdx.x, i = blockIdx.x * 256 + t;
    s[t] = (i < NN) ? deg[i] : 0;
    __syncthreads();
    for (int off = 128; off > 0; off >>= 1) {
        if (t < off) s[t] += s[t + off];
        __syncthreads();
    }
    if (t == 0) bsums[blockIdx.x] = s[0];
}

// merged scan2+scan3: every block scans the 196 chunk sums locally, then its chunk
__global__ void scan23_kernel(const int* __restrict__ deg, const int* __restrict__ bsums,
                              int* __restrict__ rowptr, int* __restrict__ cursor) {
    __shared__ int offs[256];
    __shared__ int s[256];
    int t = threadIdx.x, blk = blockIdx.x;
    offs[t] = (t < NB) ? bsums[t] : 0;
    __syncthreads();
    for (int o = 1; o < 256; o <<= 1) {
        int x = (t >= o) ? offs[t - o] : 0;
        __syncthreads();
        offs[t] += x;
        __syncthreads();
    }
    int chunk_off = (blk > 0) ? offs[blk - 1] : 0;   // exclusive offset of this chunk
    int i = blk * 256 + t;
    int v = (i < NN) ? deg[i] : 0;
    s[t] = v;
    __syncthreads();
    for (int o = 1; o < 256; o <<= 1) {
        int x = (t >= o) ? s[t - o] : 0;
        __syncthreads();
        s[t] += x;
        __syncthreads();
    }
    if (i < NN) {
        int rp = chunk_off + s[t] - v;
        rowptr[i] = rp;
        cursor[i] = rp;
    }
    if (blk == 0 && t == 0) rowptr[NN] = NE;
}

// scatter edges into CSR slots; ushort col, nt reads of the edge streams
__global__ void fill_kernel(const int* __restrict__ src, const int* __restrict__ dst,
                            int* __restrict__ cursor, unsigned short* __restrict__ col) {
    int e = blockIdx.x * 256 + threadIdx.x;
    if (e < NE) {
        int sv = ntload_i(&src[e]);
        int slot = atomicAdd(&cursor[ntload_i(&dst[e])], 1);
        col[slot] = (unsigned short)sv;
    }
}

// ---------------- layer-1 aggregation over raw xd (32 feats = 8 f4) ------------
__global__ void agg32_kernel(const f4* __restrict__ g4, const int* __restrict__ rowptr,
                             const unsigned short* __restrict__ col, const float* __restrict__ dinv,
                             float* __restrict__ out) {
    int lane = threadIdx.x & 63;
    int v = blockIdx.x * 4 + (threadIdx.x >> 6);
    int slot = lane >> 3, fq = lane & 7;
    int beg = rowptr[v], end = rowptr[v + 1];
    f4 acc = {0.f, 0.f, 0.f, 0.f};
    for (int base = beg; base < end; base += 32) {
        f4 a[4];
        float w[4];
#pragma unroll
        for (int j = 0; j < 4; ++j) {
            int e = base + slot + j * 8;
            int ce = (e < end) ? e : (end - 1);
            w[j] = (e < end) ? 1.f : 0.f;
            int u = col[ce];
            a[j] = g4[(long)u * 8 + fq];
        }
#pragma unroll
        for (int j = 0; j < 4; ++j) acc += w[j] * a[j];
    }
#pragma unroll
    for (int m = 8; m < 64; m <<= 1) {
        acc.x += __shfl_xor(acc.x, m);
        acc.y += __shfl_xor(acc.y, m);
        acc.z += __shfl_xor(acc.z, m);
        acc.w += __shfl_xor(acc.w, m);
    }
    f4 self = g4[(long)v * 8 + fq];
    float d = dinv[v];
    acc = d * (acc + self);
    if (slot < 4) {
        float comp = (slot == 0) ? acc.x : (slot == 1) ? acc.y : (slot == 2) ? acc.z : acc.w;
        out[(long)v * 32 + 4 * fq + slot] = comp;
    }
}

// ---------------- agg4h: half-split (32 feats = 8 f4), 16 nodes per wave ----------
// g layout half-major [2][NN][32]; half h pinned to XCDs {4h..4h+3} via bi&7.
template <bool POOL>
__global__ void agg4h_kernel(const f4* __restrict__ g, const int* __restrict__ rowptr,
                             const unsigned short* __restrict__ col, const float* __restrict__ dinv,
                             const f4* __restrict__ bias4, float* __restrict__ out,
                             const int* __restrict__ batch, float* __restrict__ pooled,
                             float* __restrict__ counts) {
    int tid = threadIdx.x, lane = tid & 63, w = tid >> 6;
    int bi = blockIdx.x;
    int h = (bi & 7) >> 2;
    int idx = ((bi >> 3) << 2) | (bi & 3);
    int base = idx * 64 + w * 16;
    if (base >= NN) return;
    int slot = lane >> 3, fq = lane & 7;
    const f4* gb = g + (long)h * NN * 8;
    // lane-parallel rowptr preload: lane i<17 holds rowptr[base+i]
    int li = base + ((lane < 17) ? lane : 16);
    if (li > NN) li = NN;
    int rpv = rowptr[li];
#pragma unroll 1
    for (int i = 0; i < 16; ++i) {
        int v = base + i;
        if (v >= NN) break;
        int beg = __shfl(rpv, i), end = __shfl(rpv, i + 1);
        f4 acc = {0.f, 0.f, 0.f, 0.f};
        for (int b0 = beg; b0 < end; b0 += 32) {
            f4 a[4];
            float wt[4];
#pragma unroll
            for (int j = 0; j < 4; ++j) {
                int e = b0 + slot + j * 8;
                int ce = (e < end) ? e : (end - 1);
                wt[j] = (e < end) ? 1.f : 0.f;
                int u = col[ce];
                a[j] = gb[(long)u * 8 + fq];   // 128B row from pinned half-plane
            }
#pragma unroll
            for (int j = 0; j < 4; ++j) acc += wt[j] * a[j];
        }
#pragma unroll
        for (int m = 8; m < 64; m <<= 1) {
            acc.x += __shfl_xor(acc.x, m);
            acc.y += __shfl_xor(acc.y, m);
            acc.z += __shfl_xor(acc.z, m);
            acc.w += __shfl_xor(acc.w, m);
        }
        f4 self = gb[(long)v * 8 + fq];
        float d = dinv[v];
        f4 bb = bias4[h * 8 + fq];
        f4 hv;
        hv.x = fmaxf(fmaf(d, acc.x + self.x, bb.x), 0.f);
        hv.y = fmaxf(fmaf(d, acc.y + self.y, bb.y), 0.f);
        hv.z = fmaxf(fmaf(d, acc.z + self.z, bb.z), 0.f);
        hv.w = fmaxf(fmaf(d, acc.w + self.w, bb.w), 0.f);
        if (slot < 4) {   // 32 lanes, 32 distinct scalars = 128B line
            float comp = (slot == 0) ? hv.x : (slot == 1) ? hv.y : (slot == 2) ? hv.z : hv.w;
            int feat = h * 32 + fq * 4 + slot;
            if (POOL) {
                atomicAdd(&pooled[(long)batch[v] * F + feat], comp);
            } else {
                out[(long)v * F + feat] = comp;
            }
        }
        if (POOL && h == 0 && lane == 0) atomicAdd(&counts[batch[v]], 1.0f);
    }
}

// ---------------- GEMM: 16 nodes/block, 256 threads -------------------------------
// RELU_BIAS: out = relu(in@W + b), row-major (layer-1)
// else:      out = dinv[n]*(in@W), HALF-MAJOR [2][NN][32] for agg4h
template <int K, bool RELU_BIAS>
__global__ void gemm_kernel(const float* __restrict__ in, const float* __restrict__ W,
                            const float* __restrict__ bias, const float* __restrict__ dinv,
                            float* __restrict__ out) {
    __shared__ float Ws[K * F];
    int t = threadIdx.x;
#pragma unroll
    for (int i = 0; i < K * F / 256; ++i) Ws[i * 256 + t] = W[i * 256 + t];
    __syncthreads();
    int f = t & 63;
    int slot = __builtin_amdgcn_readfirstlane(t >> 6);  // wave-uniform
    int n0 = blockIdx.x * 16 + slot;                    // nodes n0, n0+4, n0+8, n0+12
    float acc0 = 0.f, acc1 = 0.f, acc2 = 0.f, acc3 = 0.f;
    const float* r0 = in + (long)n0 * K;
    const float* r1 = r0 + 4 * K;
    const float* r2 = r0 + 8 * K;
    const float* r3 = r0 + 12 * K;
#pragma unroll
    for (int k = 0; k < K; ++k) {
        float w = Ws[k * F + f];
        acc0 = fmaf(r0[k], w, acc0);
        acc1 = fmaf(r1[k], w, acc1);
        acc2 = fmaf(r2[k], w, acc2);
        acc3 = fmaf(r3[k], w, acc3);
    }
    if (RELU_BIAS) {
        float b = bias[f];
        out[(long)n0 * F + f]        = fmaxf(acc0 + b, 0.f);
        out[(long)(n0 + 4) * F + f]  = fmaxf(acc1 + b, 0.f);
        out[(long)(n0 + 8) * F + f]  = fmaxf(acc2 + b, 0.f);
        out[(long)(n0 + 12) * F + f] = fmaxf(acc3 + b, 0.f);
    } else {
        int hh = f >> 5, fl = f & 31;
        float* o = out + (long)hh * NN * 32 + fl;
        o[(long)n0 * 32]        = dinv[n0] * acc0;
        o[(long)(n0 + 4) * 32]  = dinv[n0 + 4] * acc1;
        o[(long)(n0 + 8) * 32]  = dinv[n0 + 8] * acc2;
        o[(long)(n0 + 12) * 32] = dinv[n0 + 12] * acc3;
    }
}

// ---------------- head: out = relu(pooled/cnt @ lw1 + lb1) @ lw2 + lb2 ------------
__global__ void head_kernel(const float* __restrict__ pooled, const float* __restrict__ counts,
                            const float* __restrict__ lw1, const float* __restrict__ lb1,
                            const float* __restrict__ lw2, const float* __restrict__ lb2,
                            float* __restrict__ out) {
    __shared__ float p[F];
    __shared__ float hid[F];
    int gid = blockIdx.x, t = threadIdx.x;
    float cnt = fmaxf(counts[gid], 1.0f);
    p[t] = pooled[(long)gid * F + t] / cnt;
    __syncthreads();
    float acc = lb1[t];
#pragma unroll 8
    for (int k = 0; k < F; ++k) acc = fmaf(p[k], lw1[k * F + t], acc);
    hid[t] = fmaxf(acc, 0.f);
    __syncthreads();
    if (t < 2) {
        float a = lb2[t];
#pragma unroll 8
        for (int k = 0; k < F; ++k) a = fmaf(hid[k], lw2[k * 2 + t], a);
        out[(long)gid * 2 + t] = a;
    }
}

extern "C" void kernel_launch(void* const* d_in, const int* in_sizes, int n_in,
                              void* d_out, int out_size, void* d_ws, size_t ws_size,
                              hipStream_t stream) {
    const float* x    = (const float*)d_in[0];
    const int*   ei   = (const int*)d_in[1];   // [2, NE]: src then dst
    const int*   bat  = (const int*)d_in[2];
    const float* W1   = (const float*)d_in[3];
    const float* b1   = (const float*)d_in[4];
    const float* W2   = (const float*)d_in[5];
    const float* b2   = (const float*)d_in[6];
    const float* W3   = (const float*)d_in[7];
    const float* b3   = (const float*)d_in[8];
    const float* lw1  = (const float*)d_in[9];
    const float* lb1  = (const float*)d_in[10];
    const float* lw2  = (const float*)d_in[11];
    const float* lb2  = (const float*)d_in[12];
    float* out = (float*)d_out;

    const int* src = ei;
    const int* dst = ei + NE;

    // workspace carve-up (256B aligned)
    char* ws = (char*)d_ws;
    size_t off = 0;
    auto carve = [&](size_t bytes) {
        void* p = ws + off;
        off += (bytes + 255) & ~(size_t)255;
        return p;
    };
    int*   deg     = (int*)carve(NN * 4);
    float* dinv    = (float*)carve(NN * 4);
    int*   rowptr  = (int*)carve((NN + 1) * 4);
    int*   cursor  = (int*)carve(NN * 4);
    int*   bsums   = (int*)carve(256 * 4);
    unsigned short* col = (unsigned short*)carve((size_t)NE * 2);
    float* xd      = (float*)carve((size_t)NN * 32 * 4);  // row-major
    float* sbuf    = (float*)carve((size_t)NN * 32 * 4);  // row-major
    float* bufA    = (float*)carve((size_t)NN * F * 4);   // row-major h
    float* bufB    = (float*)carve((size_t)NN * F * 4);   // half-major g [2][NN][32]
    float* pooled  = (float*)carve((size_t)NG * F * 4 + NG * 4);
    float* counts  = pooled + (size_t)NG * F;

    hipMemsetAsync(deg, 0, NN * 4, stream);
    hipMemsetAsync(pooled, 0, ((size_t)NG * F + NG) * 4, stream);

    deg_kernel<<<(NE + 255) / 256, 256, 0, stream>>>(dst, deg);
    scalex_kernel<<<(NN * 8 + 255) / 256, 256, 0, stream>>>(deg, (const float4*)x, dinv, (float4*)xd);
    scan1_kernel<<<NB, 256, 0, stream>>>(deg, bsums);
    scan23_kernel<<<NB, 256, 0, stream>>>(deg, bsums, rowptr, cursor);
    fill_kernel<<<(NE + 255) / 256, 256, 0, stream>>>(src, dst, cursor, col);

    const int gridN = NN / 4;      // 12500 blocks (agg32)
    const int gridH = 196 * 8;     // 1568 blocks (agg4h: 2 halves x 784 idx)
    const int gridG = NN / 16;     // 3125 blocks (gemm)

    // layer 1: aggregate raw 32-feat xd, then GEMM with fused bias+relu
    agg32_kernel<<<gridN, 256, 0, stream>>>((const f4*)xd, rowptr, col, dinv, sbuf);
    gemm_kernel<32, true><<<gridG, 256, 0, stream>>>(sbuf, W1, b1, dinv, bufA);

    // layer 2: g = dinv*(h1@W2) half-major; half-split 16-node agg with bias+relu
    gemm_kernel<64, false><<<gridG, 256, 0, stream>>>(bufA, W2, nullptr, dinv, bufB);
    agg4h_kernel<false><<<gridH, 256, 0, stream>>>((const f4*)bufB, rowptr, col, dinv,
                                                   (const f4*)b2, bufA,
                                                   nullptr, nullptr, nullptr);
    // layer 3: same, final fuses mean-pool atomics
    gemm_kernel<64, false><<<gridG, 256, 0, stream>>>(bufA, W3, nullptr, dinv, bufB);
    agg4h_kernel<true><<<gridH, 256, 0, stream>>>((const f4*)bufB, rowptr, col, dinv,
                                                  (const f4*)b3, nullptr,
                                                  bat, pooled, counts);
    // head MLP
    head_kernel<<<NG, 64, 0, stream>>>(pooled, counts, lw1, lb1, lw2, lb2, out);
}